// Round 1
// baseline (650.800 us; speedup 1.0000x reference)
//
#include <hip/hip_runtime.h>

#define N_NODES 50000
#define N_EDGES 800000

// ---------------------------------------------------------------- edge utils

// Detect int32 vs int64 edge_index: if data is int64 (values < 2^31), every
// odd 32-bit word is 0. Sample 4096 odd words; OR them into *flag.
__global__ __launch_bounds__(256) void k_detect(const int* __restrict__ ei, int* __restrict__ flag) {
    int t = threadIdx.x;
    int v = 0;
    for (int i = 1 + 2 * t; i < 8192; i += 512) v |= ei[i];
    if (v) atomicOr(flag, 1);
}

// Convert edge_index to int32 regardless of source width. *flag==1 -> int32.
__global__ __launch_bounds__(256) void k_cvt(const void* __restrict__ eiraw, const int* __restrict__ flag,
                                             int* __restrict__ ei32) {
    int e = blockIdx.x * 256 + threadIdx.x;
    if (e >= 2 * N_EDGES) return;
    if (*flag) ei32[e] = ((const int*)eiraw)[e];
    else       ei32[e] = (int)(((const long long*)eiraw)[e]);
}

// ---------------------------------------------------------------- CSR build

__global__ __launch_bounds__(256) void k_deg(const int* __restrict__ ei, const float* __restrict__ w,
                                             float* __restrict__ degw, int* __restrict__ cnt) {
    int e = blockIdx.x * 256 + threadIdx.x;
    if (e >= N_EDGES) return;
    int r = ei[e];
    atomicAdd(&degw[r], w[e]);
    atomicAdd(&cnt[r], 1);
}

__global__ __launch_bounds__(256) void k_dinv(const float* __restrict__ degw, float* __restrict__ dinv) {
    int i = blockIdx.x * 256 + threadIdx.x;
    if (i >= N_NODES) return;
    float d = degw[i];
    dinv[i] = (d > 0.f) ? rsqrtf(d) : 0.f;
}

__global__ __launch_bounds__(256) void k_scan1(const int* __restrict__ cnt, int* __restrict__ rp,
                                               int* __restrict__ part) {
    __shared__ int s[256];
    int t = threadIdx.x, i = blockIdx.x * 256 + t;
    int v = (i < N_NODES) ? cnt[i] : 0;
    s[t] = v; __syncthreads();
    for (int d = 1; d < 256; d <<= 1) {
        int add = (t >= d) ? s[t - d] : 0;
        __syncthreads();
        s[t] += add;
        __syncthreads();
    }
    if (i < N_NODES) rp[i] = s[t] - v;          // exclusive within block
    if (t == 255) part[blockIdx.x] = s[255];
}

__global__ __launch_bounds__(256) void k_scan2(int* __restrict__ part, int nb) {
    __shared__ int s[256];
    int t = threadIdx.x;
    int v = (t < nb) ? part[t] : 0;
    s[t] = v; __syncthreads();
    for (int d = 1; d < 256; d <<= 1) {
        int add = (t >= d) ? s[t - d] : 0;
        __syncthreads();
        s[t] += add;
        __syncthreads();
    }
    if (t < nb) part[t] = s[t] - v;             // exclusive
}

__global__ __launch_bounds__(256) void k_scan3(int* __restrict__ rp, const int* __restrict__ part,
                                               int* __restrict__ cur) {
    int i = blockIdx.x * 256 + threadIdx.x;
    if (i < N_NODES) {
        int v = rp[i] + part[blockIdx.x];
        rp[i] = v;
        cur[i] = v;
    }
    if (i == 0) rp[N_NODES] = N_EDGES;
}

__global__ __launch_bounds__(256) void k_scatter(const int* __restrict__ ei, const float* __restrict__ w,
                                                 const float* __restrict__ dinv, int* __restrict__ cur,
                                                 int* __restrict__ colp, float* __restrict__ nwp) {
    int e = blockIdx.x * 256 + threadIdx.x;
    if (e >= N_EDGES) return;
    int r = ei[e], c = ei[N_EDGES + e];
    int pos = atomicAdd(&cur[r], 1);
    colp[pos] = c;
    nwp[pos] = dinv[r] * w[e] * dinv[c];
}

// ---------------------------------------------------------------- SpMV (dual)
// One wave per node, lane = channel. U = A * V for two matrices at once
// (shares colp/nwp loads). Coalesced 256B row gathers, accumulation in regs.

__global__ __launch_bounds__(256) void k_spmv2(const float* __restrict__ vx, const float* __restrict__ vh,
                                               float* __restrict__ ux, float* __restrict__ uh,
                                               const int* __restrict__ rp, const int* __restrict__ colp,
                                               const float* __restrict__ nwp) {
    int wid = threadIdx.x >> 6, lane = threadIdx.x & 63;
    int node = blockIdx.x * 4 + wid;
    if (node >= N_NODES) return;
    int s = rp[node], e = rp[node + 1];
    float ax = 0.f, ah = 0.f;
    for (int j = s; j < e; j++) {
        int c = colp[j];
        float ww = nwp[j];
        ax = fmaf(ww, vx[c * 64 + lane], ax);
        ah = fmaf(ww, vh[c * 64 + lane], ah);
    }
    ux[node * 64 + lane] = ax;
    uh[node * 64 + lane] = ah;
}

// ---------------------------------------------------------------- weight fold
// In = [X, U1x, U2x, H, U1h, U2h]  (U1 = A*V, U2 = A*A*V; T1 = -U1, T2 = 2U2-V)
// Wall[k][g*64+c], k = s*64+kk:
//   s=0: Wx_g[0]-Wx_g[2]   s=1: -Wx_g[1]   s=2: 2*Wx_g[2]
//   s=3: Wh_g[0]-Wh_g[2]   s=4: -Wh_g[1]   s=5: 2*Wh_g[2]
// ball[g*64+c] = bx_g[c] + bh_g[c] + bgate_g[c]

__global__ __launch_bounds__(256) void k_wprep(
    const float* __restrict__ Wxi, const float* __restrict__ Whi,
    const float* __restrict__ Wxf, const float* __restrict__ Whf,
    const float* __restrict__ Wxc, const float* __restrict__ Whc,
    const float* __restrict__ Wxo, const float* __restrict__ Who,
    const float* __restrict__ bxi, const float* __restrict__ bhi,
    const float* __restrict__ bxf, const float* __restrict__ bhf,
    const float* __restrict__ bxc, const float* __restrict__ bhc,
    const float* __restrict__ bxo, const float* __restrict__ bho,
    const float* __restrict__ bgi, const float* __restrict__ bgf,
    const float* __restrict__ bgc, const float* __restrict__ bgo,
    float* __restrict__ Wall, float* __restrict__ ball) {
    int b = blockIdx.x, t = threadIdx.x;
    int g = t >> 6, c = t & 63;
    const float* WX = (g == 0) ? Wxi : (g == 1) ? Wxf : (g == 2) ? Wxc : Wxo;
    const float* WH = (g == 0) ? Whi : (g == 1) ? Whf : (g == 2) ? Whc : Who;
    if (b < 384) {
        int s = b >> 6, kk = b & 63;
        int idx = kk * 64 + c;
        float v;
        if (s == 0)      v = WX[idx] - WX[2 * 4096 + idx];
        else if (s == 1) v = -WX[4096 + idx];
        else if (s == 2) v = 2.f * WX[2 * 4096 + idx];
        else if (s == 3) v = WH[idx] - WH[2 * 4096 + idx];
        else if (s == 4) v = -WH[4096 + idx];
        else             v = 2.f * WH[2 * 4096 + idx];
        Wall[b * 256 + t] = v;
    } else {
        const float* BX = (g == 0) ? bxi : (g == 1) ? bxf : (g == 2) ? bxc : bxo;
        const float* BH = (g == 0) ? bhi : (g == 1) ? bhf : (g == 2) ? bhc : bho;
        const float* BG = (g == 0) ? bgi : (g == 1) ? bgf : (g == 2) ? bgc : bgo;
        ball[t] = BX[c] + BH[c] + BG[c];
    }
}

// ---------------------------------------------------------------- fused GEMM + gates
// [50000,384] @ [384,256] with LSTM epilogue. Block: 64 nodes x 256 cols,
// 256 threads, per-thread 4 nodes x 16 cols (4 per gate -> epilogue is local).

__global__ __launch_bounds__(256) void k_gemm_gate(
    const float* __restrict__ X, const float* __restrict__ U1x, const float* __restrict__ U2x,
    const float* __restrict__ H, const float* __restrict__ U1h, const float* __restrict__ U2h,
    const float* __restrict__ Wall, const float* __restrict__ ball,
    const float* __restrict__ C, float* __restrict__ out) {
    __shared__ __align__(16) float As[32 * 68];   // [k][node], stride 68 keeps b128 aligned
    __shared__ __align__(16) float Bs[32 * 256];  // [k][col]

    int t = threadIdx.x;
    int tx = t & 15, ty = t >> 4;
    int node0 = blockIdx.x * 64;

    float acc[4][16];
#pragma unroll
    for (int i = 0; i < 4; i++)
#pragma unroll
        for (int j = 0; j < 16; j++) acc[i][j] = 0.f;

    int kl = t & 31, nl0 = t >> 5;       // A staging: kl 0..31, 8 node rows
    int c4 = (t & 63) * 4, kl0 = t >> 6; // B staging: float4 cols, 8 k rows

    for (int kt = 0; kt < 12; kt++) {
        int sel = kt >> 1;
        const float* sp = (sel == 0) ? X : (sel == 1) ? U1x : (sel == 2) ? U2x
                        : (sel == 3) ? H : (sel == 4) ? U1h : U2h;
        int kbase = (kt & 1) * 32;
        int k0 = kt * 32;

        __syncthreads();
#pragma unroll
        for (int i = 0; i < 8; i++) {
            int nl = nl0 + i * 8;
            int n = node0 + nl;
            As[kl * 68 + nl] = (n < N_NODES) ? sp[n * 64 + kbase + kl] : 0.f;
        }
#pragma unroll
        for (int i = 0; i < 8; i++) {
            int krow = kl0 + i * 4;
            *(float4*)(Bs + krow * 256 + c4) = *(const float4*)(Wall + (k0 + krow) * 256 + c4);
        }
        __syncthreads();

#pragma unroll 8
        for (int kk = 0; kk < 32; kk++) {
            float4 av = *(const float4*)(As + kk * 68 + ty * 4);
            float ar[4] = {av.x, av.y, av.z, av.w};
#pragma unroll
            for (int g = 0; g < 4; g++) {
                float4 bv = *(const float4*)(Bs + kk * 256 + g * 64 + tx * 4);
                float br[4] = {bv.x, bv.y, bv.z, bv.w};
#pragma unroll
                for (int i = 0; i < 4; i++)
#pragma unroll
                    for (int jj = 0; jj < 4; jj++)
                        acc[i][g * 4 + jj] = fmaf(ar[i], br[jj], acc[i][g * 4 + jj]);
            }
        }
    }

    // epilogue: acc[i][g*4+jj] is pre-activation of gate g, node node0+ty*4+i,
    // channel c = tx*4+jj. Gates: 0=I, 1=F, 2=T(cell cand), 3=O.
    float ba[4][4];
#pragma unroll
    for (int g = 0; g < 4; g++) {
        float4 b4 = *(const float4*)(ball + g * 64 + tx * 4);
        ba[g][0] = b4.x; ba[g][1] = b4.y; ba[g][2] = b4.z; ba[g][3] = b4.w;
    }
#pragma unroll
    for (int i = 0; i < 4; i++) {
        int node = node0 + ty * 4 + i;
        if (node >= N_NODES) continue;
        float4 c4v = *(const float4*)(C + node * 64 + tx * 4);
        float Cold[4] = {c4v.x, c4v.y, c4v.z, c4v.w};
        float hn[4], cn[4];
#pragma unroll
        for (int jj = 0; jj < 4; jj++) {
            float Ip = acc[i][0 + jj]  + ba[0][jj];
            float Fp = acc[i][4 + jj]  + ba[1][jj];
            float Tp = acc[i][8 + jj]  + ba[2][jj];
            float Op = acc[i][12 + jj] + ba[3][jj];
            float ig = 1.f / (1.f + __expf(-Ip));
            float fg = 1.f / (1.f + __expf(-Fp));
            float tg = tanhf(Tp);
            float og = 1.f / (1.f + __expf(-Op));
            float cv = fmaf(fg, Cold[jj], ig * tg);
            cn[jj] = cv;
            hn[jj] = og * tanhf(cv);
        }
        *(float4*)(out + node * 64 + tx * 4) = make_float4(hn[0], hn[1], hn[2], hn[3]);
        *(float4*)(out + N_NODES * 64 + node * 64 + tx * 4) = make_float4(cn[0], cn[1], cn[2], cn[3]);
    }
}

// ---------------------------------------------------------------- launch

extern "C" void kernel_launch(void* const* d_in, const int* in_sizes, int n_in,
                              void* d_out, int out_size, void* d_ws, size_t ws_size,
                              hipStream_t stream) {
    const float* X   = (const float*)d_in[0];
    const void*  ei  = d_in[1];
    const float* w   = (const float*)d_in[2];
    const float* H   = (const float*)d_in[3];
    const float* C   = (const float*)d_in[4];
    const float* Wxi = (const float*)d_in[5];  const float* bxi = (const float*)d_in[6];
    const float* Whi = (const float*)d_in[7];  const float* bhi = (const float*)d_in[8];
    const float* Wxf = (const float*)d_in[9];  const float* bxf = (const float*)d_in[10];
    const float* Whf = (const float*)d_in[11]; const float* bhf = (const float*)d_in[12];
    const float* Wxc = (const float*)d_in[13]; const float* bxc = (const float*)d_in[14];
    const float* Whc = (const float*)d_in[15]; const float* bhc = (const float*)d_in[16];
    const float* Wxo = (const float*)d_in[17]; const float* bxo = (const float*)d_in[18];
    const float* Who = (const float*)d_in[19]; const float* bho = (const float*)d_in[20];
    const float* bgi = (const float*)d_in[21]; const float* bgf = (const float*)d_in[22];
    const float* bgc = (const float*)d_in[23]; const float* bgo = (const float*)d_in[24];
    float* out = (float*)d_out;

    char* ws = (char*)d_ws;
    size_t off = 0;
    auto alloc = [&](size_t bytes) -> char* {
        char* p = ws + off;
        off = (off + bytes + 255) & ~(size_t)255;
        return p;
    };
    float* degw = (float*)alloc(N_NODES * 4);
    int*   cnt  = (int*)alloc(N_NODES * 4);
    int*   rp   = (int*)alloc((N_NODES + 1) * 4);
    int*   cur  = (int*)alloc(N_NODES * 4);
    int*   part = (int*)alloc(256 * 4);
    float* dinv = (float*)alloc(N_NODES * 4);
    int*   flag = (int*)alloc(4);
    int*   ei32 = (int*)alloc(2 * N_EDGES * 4);
    int*   colp = (int*)alloc(N_EDGES * 4);
    float* nwp  = (float*)alloc(N_EDGES * 4);
    float* U1x  = (float*)alloc((size_t)N_NODES * 64 * 4);
    float* U2x  = (float*)alloc((size_t)N_NODES * 64 * 4);
    float* U1h  = (float*)alloc((size_t)N_NODES * 64 * 4);
    float* U2h  = (float*)alloc((size_t)N_NODES * 64 * 4);
    float* Wall = (float*)alloc(384 * 256 * 4);
    float* ball = (float*)alloc(256 * 4);
    (void)ws_size; (void)in_sizes; (void)n_in; (void)out_size;

    hipMemsetAsync(degw, 0, N_NODES * 4, stream);
    hipMemsetAsync(cnt, 0, N_NODES * 4, stream);
    hipMemsetAsync(flag, 0, 4, stream);

    int nbN = (N_NODES + 255) / 256;   // 196
    int nbE = (N_EDGES + 255) / 256;   // 3125
    int nbE2 = (2 * N_EDGES + 255) / 256;

    k_detect<<<1, 256, 0, stream>>>((const int*)ei, flag);
    k_cvt<<<nbE2, 256, 0, stream>>>(ei, flag, ei32);
    k_deg<<<nbE, 256, 0, stream>>>(ei32, w, degw, cnt);
    k_dinv<<<nbN, 256, 0, stream>>>(degw, dinv);
    k_scan1<<<nbN, 256, 0, stream>>>(cnt, rp, part);
    k_scan2<<<1, 256, 0, stream>>>(part, nbN);
    k_scan3<<<nbN, 256, 0, stream>>>(rp, part, cur);
    k_scatter<<<nbE, 256, 0, stream>>>(ei32, w, dinv, cur, colp, nwp);
    k_wprep<<<385, 256, 0, stream>>>(Wxi, Whi, Wxf, Whf, Wxc, Whc, Wxo, Who,
                                     bxi, bhi, bxf, bhf, bxc, bhc, bxo, bho,
                                     bgi, bgf, bgc, bgo, Wall, ball);
    k_spmv2<<<(N_NODES + 3) / 4, 256, 0, stream>>>(X, H, U1x, U1h, rp, colp, nwp);
    k_spmv2<<<(N_NODES + 3) / 4, 256, 0, stream>>>(U1x, U1h, U2x, U2h, rp, colp, nwp);
    k_gemm_gate<<<(N_NODES + 63) / 64, 256, 0, stream>>>(X, U1x, U2x, H, U1h, U2h,
                                                         Wall, ball, C, out);
}

// Round 2
// 420.686 us; speedup vs baseline: 1.5470x; 1.5470x over previous
//
#include <hip/hip_runtime.h>

#define N_NODES 50000
#define N_PAD   50048
#define N_EDGES 800000

typedef __attribute__((ext_vector_type(8))) short bf16x8;
typedef __attribute__((ext_vector_type(4))) float f32x4;

__device__ __forceinline__ unsigned short f2bf(float f) {
    unsigned u = __float_as_uint(f);
    u = (u + 0x7fffu + ((u >> 16) & 1u)) >> 16;
    return (unsigned short)u;
}

// ---------------------------------------------------------------- edge utils

__global__ __launch_bounds__(256) void k_detect(const int* __restrict__ ei, int* __restrict__ flag) {
    int t = threadIdx.x;
    int v = 0;
    for (int i = 1 + 2 * t; i < 8192; i += 512) v |= ei[i];
    if (v) atomicOr(flag, 1);
}

// convert edge_index to int32 (either source width) + weighted degree + count
__global__ __launch_bounds__(256) void k_cvt_deg(const void* __restrict__ eiraw, const int* __restrict__ flag,
                                                 const float* __restrict__ w, int* __restrict__ ei32,
                                                 float* __restrict__ degw, int* __restrict__ cnt) {
    int e = blockIdx.x * 256 + threadIdx.x;
    if (e >= 2 * N_EDGES) return;
    int v = (*flag) ? ((const int*)eiraw)[e] : (int)(((const long long*)eiraw)[e]);
    ei32[e] = v;
    if (e < N_EDGES) {
        atomicAdd(&degw[v], w[e]);
        atomicAdd(&cnt[v], 1);
    }
}

// ---------------------------------------------------------------- CSR build

__global__ __launch_bounds__(256) void k_scan1(const int* __restrict__ cnt, int* __restrict__ rp,
                                               int* __restrict__ part, const float* __restrict__ degw,
                                               float* __restrict__ dinv) {
    __shared__ int s[256];
    int t = threadIdx.x, i = blockIdx.x * 256 + t;
    int v = (i < N_NODES) ? cnt[i] : 0;
    s[t] = v; __syncthreads();
    for (int d = 1; d < 256; d <<= 1) {
        int add = (t >= d) ? s[t - d] : 0;
        __syncthreads();
        s[t] += add;
        __syncthreads();
    }
    if (i < N_NODES) {
        rp[i] = s[t] - v;
        float dg = degw[i];
        dinv[i] = (dg > 0.f) ? rsqrtf(dg) : 0.f;
    }
    if (t == 255) part[blockIdx.x] = s[255];
}

__global__ __launch_bounds__(256) void k_scan2(int* __restrict__ part, int nb) {
    __shared__ int s[256];
    int t = threadIdx.x;
    int v = (t < nb) ? part[t] : 0;
    s[t] = v; __syncthreads();
    for (int d = 1; d < 256; d <<= 1) {
        int add = (t >= d) ? s[t - d] : 0;
        __syncthreads();
        s[t] += add;
        __syncthreads();
    }
    if (t < nb) part[t] = s[t] - v;
}

__global__ __launch_bounds__(256) void k_scan3(int* __restrict__ rp, const int* __restrict__ part,
                                               int* __restrict__ cur) {
    int i = blockIdx.x * 256 + threadIdx.x;
    if (i < N_NODES) {
        int v = rp[i] + part[blockIdx.x];
        rp[i] = v;
        cur[i] = v;
    }
    if (i == 0) rp[N_NODES] = N_EDGES;
}

__global__ __launch_bounds__(256) void k_scatter(const int* __restrict__ ei, const float* __restrict__ w,
                                                 const float* __restrict__ dinv, int* __restrict__ cur,
                                                 int* __restrict__ colp, float* __restrict__ nwp) {
    int e = blockIdx.x * 256 + threadIdx.x;
    if (e >= N_EDGES) return;
    int r = ei[e], c = ei[N_EDGES + e];
    int pos = atomicAdd(&cur[r], 1);
    colp[pos] = c;
    nwp[pos] = dinv[r] * w[e] * dinv[c];
}

// ---------------------------------------------------------------- interleave X||H -> bf16 [node][128]

__global__ __launch_bounds__(256) void k_interleave(const float* __restrict__ X, const float* __restrict__ H,
                                                    unsigned short* __restrict__ XH) {
    int t = blockIdx.x * 256 + threadIdx.x;   // one thread per 4 channels
    if (t >= N_NODES * 32) return;
    int node = t >> 5, g = t & 31;
    float4 v = (g < 16) ? *(const float4*)(X + (size_t)node * 64 + g * 4)
                        : *(const float4*)(H + (size_t)node * 64 + (g - 16) * 4);
    ushort4 o;
    o.x = f2bf(v.x); o.y = f2bf(v.y); o.z = f2bf(v.z); o.w = f2bf(v.w);
    *(ushort4*)(XH + (size_t)node * 128 + g * 4) = o;
}

// ---------------------------------------------------------------- SpMV: dst = A * src (bf16 in/out, fp32 accum)
// one wave per node; lane owns channel pair (2*lane, 2*lane+1); 256B coalesced row gather per edge.

__global__ __launch_bounds__(256) void k_spmv_bf(const unsigned short* __restrict__ src,
                                                 unsigned short* __restrict__ dst,
                                                 const int* __restrict__ rp, const int* __restrict__ colp,
                                                 const float* __restrict__ nwp) {
    int wid = threadIdx.x >> 6, lane = threadIdx.x & 63;
    int node = blockIdx.x * 4 + wid;
    if (node >= N_NODES) return;
    int s = rp[node], e = rp[node + 1];
    float a0 = 0.f, a1 = 0.f;
    int j = s;
    for (; j + 2 <= e; j += 2) {                 // 2-edge unroll: two independent gather chains
        int c0 = colp[j], c1 = colp[j + 1];
        float w0 = nwp[j], w1 = nwp[j + 1];
        unsigned v0 = *(const unsigned*)(src + (size_t)c0 * 128 + lane * 2);
        unsigned v1 = *(const unsigned*)(src + (size_t)c1 * 128 + lane * 2);
        a0 = fmaf(w0, __uint_as_float(v0 << 16), a0);
        a1 = fmaf(w0, __uint_as_float(v0 & 0xffff0000u), a1);
        a0 = fmaf(w1, __uint_as_float(v1 << 16), a0);
        a1 = fmaf(w1, __uint_as_float(v1 & 0xffff0000u), a1);
    }
    if (j < e) {
        int c0 = colp[j];
        float w0 = nwp[j];
        unsigned v0 = *(const unsigned*)(src + (size_t)c0 * 128 + lane * 2);
        a0 = fmaf(w0, __uint_as_float(v0 << 16), a0);
        a1 = fmaf(w0, __uint_as_float(v0 & 0xffff0000u), a1);
    }
    unsigned o = (unsigned)f2bf(a0) | ((unsigned)f2bf(a1) << 16);
    *(unsigned*)(dst + (size_t)node * 128 + lane * 2) = o;
}

// ---------------------------------------------------------------- weight fold + pre-swizzle to MFMA B-frag order
// A(k) = [XH | U1 | U2] with k = b*128 + ch; ch<64 -> x-part, ch>=64 -> h-part.
// T0=V, T1=-U1, T2=2*U2-V fold:
//   b=0: W[0]-W[2]   b=1: -W[1]   b=2: 2*W[2]
// Wf layout: [ks(12)][nt(16)][lane(64)][j(8)] bf16, lane holds B[k=ks*32+(l>>4)*8+j][n=nt*16+(l&15)].

__global__ __launch_bounds__(256) void k_wprep(
    const float* __restrict__ Wxi, const float* __restrict__ Whi,
    const float* __restrict__ Wxf, const float* __restrict__ Whf,
    const float* __restrict__ Wxc, const float* __restrict__ Whc,
    const float* __restrict__ Wxo, const float* __restrict__ Who,
    const float* __restrict__ bxi, const float* __restrict__ bhi,
    const float* __restrict__ bxf, const float* __restrict__ bhf,
    const float* __restrict__ bxc, const float* __restrict__ bhc,
    const float* __restrict__ bxo, const float* __restrict__ bho,
    const float* __restrict__ bgi, const float* __restrict__ bgf,
    const float* __restrict__ bgc, const float* __restrict__ bgo,
    unsigned short* __restrict__ Wf, float* __restrict__ ball) {
    int b = blockIdx.x, t = threadIdx.x;
    if (b < 48) {
        int flat = b * 256 + t;                    // (ks, nt, lane)
        int l = flat & 63, nt = (flat >> 6) & 15, ks = flat >> 10;
        int n = nt * 16 + (l & 15);
        int g = n >> 6, c = n & 63;
        const float* WX = (g == 0) ? Wxi : (g == 1) ? Wxf : (g == 2) ? Wxc : Wxo;
        const float* WH = (g == 0) ? Whi : (g == 1) ? Whf : (g == 2) ? Whc : Who;
        int k0 = ks * 32 + (l >> 4) * 8;
        unsigned short ov[8];
#pragma unroll
        for (int j = 0; j < 8; j++) {
            int k = k0 + j;
            int bsel = k >> 7, ch = k & 127;
            const float* W = (ch < 64) ? WX : WH;
            int kk = ch & 63;
            float v;
            if (bsel == 0)      v = W[kk * 64 + c] - W[2 * 4096 + kk * 64 + c];
            else if (bsel == 1) v = -W[4096 + kk * 64 + c];
            else                v = 2.f * W[2 * 4096 + kk * 64 + c];
            ov[j] = f2bf(v);
        }
        uint4 o;
        o.x = (unsigned)ov[0] | ((unsigned)ov[1] << 16);
        o.y = (unsigned)ov[2] | ((unsigned)ov[3] << 16);
        o.z = (unsigned)ov[4] | ((unsigned)ov[5] << 16);
        o.w = (unsigned)ov[6] | ((unsigned)ov[7] << 16);
        *(uint4*)(Wf + (size_t)flat * 8) = o;
    } else {
        int g = t >> 6, c = t & 63;
        const float* BX = (g == 0) ? bxi : (g == 1) ? bxf : (g == 2) ? bxc : bxo;
        const float* BH = (g == 0) ? bhi : (g == 1) ? bhf : (g == 2) ? bhc : bho;
        const float* BG = (g == 0) ? bgi : (g == 1) ? bgf : (g == 2) ? bgc : bgo;
        ball[t] = BX[c] + BH[c] + BG[c];
    }
}

// ---------------------------------------------------------------- MFMA GEMM [50000,384]@[384,256] + LSTM gates
// block = 4 waves; wave = 16 rows x 256 cols = 16 acc tiles of 16x16.
// A-frag: direct global b128 (lane's 8 k-elems are contiguous). B: LDS-staged pre-swizzled frags.

__global__ __launch_bounds__(256) void k_gemm_mfma(
    const unsigned short* __restrict__ XH, const unsigned short* __restrict__ U1,
    const unsigned short* __restrict__ U2, const unsigned short* __restrict__ Wf,
    const float* __restrict__ ball, const float* __restrict__ C, float* __restrict__ out) {
    __shared__ __align__(16) unsigned short Bs[8192];   // 16 KB, one k-step of B-frags

    int t = threadIdx.x;
    int wid = t >> 6, lane = t & 63;
    int col = lane & 15, quad = lane >> 4;
    int m0 = blockIdx.x * 64 + wid * 16;
    int arow = m0 + col;                                // row this lane loads for A-frags

    f32x4 acc[16];
#pragma unroll
    for (int i = 0; i < 16; i++) acc[i] = (f32x4){0.f, 0.f, 0.f, 0.f};

    const unsigned short* srcs[3] = {XH, U1, U2};

    // loadA(ks): buffer = ks>>2, channel base = (ks&3)*32 + quad*8
    bf16x8 a_cur = *(const bf16x8*)(srcs[0] + (size_t)arow * 128 + quad * 8);

    for (int ks = 0; ks < 12; ks++) {
        __syncthreads();
        // stage this k-step's 16KB of pre-swizzled B frags (linear copy)
        const uint4* gsrc = (const uint4*)(Wf + (size_t)ks * 8192);
        uint4 st0 = gsrc[t], st1 = gsrc[t + 256], st2 = gsrc[t + 512], st3 = gsrc[t + 768];
        ((uint4*)Bs)[t] = st0; ((uint4*)Bs)[t + 256] = st1;
        ((uint4*)Bs)[t + 512] = st2; ((uint4*)Bs)[t + 768] = st3;
        bf16x8 a_nxt = a_cur;
        if (ks < 11) {
            int ks1 = ks + 1;
            a_nxt = *(const bf16x8*)(srcs[ks1 >> 2] + (size_t)arow * 128 + (ks1 & 3) * 32 + quad * 8);
        }
        __syncthreads();
#pragma unroll
        for (int nt = 0; nt < 16; nt++) {
            bf16x8 bfrag = *(const bf16x8*)(Bs + nt * 512 + lane * 8);
            acc[nt] = __builtin_amdgcn_mfma_f32_16x16x32_bf16(a_cur, bfrag, acc[nt], 0, 0, 0);
        }
        a_cur = a_nxt;
    }

    // epilogue: acc[g*4+cq][r] = pre-act of gate g, node m0+quad*4+r, channel cq*16+col
    float bI[4], bF[4], bT[4], bO[4];
#pragma unroll
    for (int cq = 0; cq < 4; cq++) {
        int c = cq * 16 + col;
        bI[cq] = ball[c]; bF[cq] = ball[64 + c]; bT[cq] = ball[128 + c]; bO[cq] = ball[192 + c];
    }
#pragma unroll
    for (int r = 0; r < 4; r++) {
        int node = m0 + quad * 4 + r;
        if (node >= N_NODES) continue;
#pragma unroll
        for (int cq = 0; cq < 4; cq++) {
            int c = cq * 16 + col;
            float Ip = acc[0 + cq][r]  + bI[cq];
            float Fp = acc[4 + cq][r]  + bF[cq];
            float Tp = acc[8 + cq][r]  + bT[cq];
            float Op = acc[12 + cq][r] + bO[cq];
            float ig = 1.f / (1.f + __expf(-Ip));
            float fg = 1.f / (1.f + __expf(-Fp));
            float tg = tanhf(Tp);
            float og = 1.f / (1.f + __expf(-Op));
            float cv = fmaf(fg, C[(size_t)node * 64 + c], ig * tg);
            out[(size_t)node * 64 + c] = og * tanhf(cv);
            out[(size_t)N_NODES * 64 + (size_t)node * 64 + c] = cv;
        }
    }
}

// ---------------------------------------------------------------- launch

extern "C" void kernel_launch(void* const* d_in, const int* in_sizes, int n_in,
                              void* d_out, int out_size, void* d_ws, size_t ws_size,
                              hipStream_t stream) {
    const float* X   = (const float*)d_in[0];
    const void*  ei  = d_in[1];
    const float* w   = (const float*)d_in[2];
    const float* H   = (const float*)d_in[3];
    const float* C   = (const float*)d_in[4];
    const float* Wxi = (const float*)d_in[5];  const float* bxi = (const float*)d_in[6];
    const float* Whi = (const float*)d_in[7];  const float* bhi = (const float*)d_in[8];
    const float* Wxf = (const float*)d_in[9];  const float* bxf = (const float*)d_in[10];
    const float* Whf = (const float*)d_in[11]; const float* bhf = (const float*)d_in[12];
    const float* Wxc = (const float*)d_in[13]; const float* bxc = (const float*)d_in[14];
    const float* Whc = (const float*)d_in[15]; const float* bhc = (const float*)d_in[16];
    const float* Wxo = (const float*)d_in[17]; const float* bxo = (const float*)d_in[18];
    const float* Who = (const float*)d_in[19]; const float* bho = (const float*)d_in[20];
    const float* bgi = (const float*)d_in[21]; const float* bgf = (const float*)d_in[22];
    const float* bgc = (const float*)d_in[23]; const float* bgo = (const float*)d_in[24];
    float* out = (float*)d_out;

    char* ws = (char*)d_ws;
    size_t off = 0;
    auto alloc = [&](size_t bytes) -> char* {
        char* p = ws + off;
        off = (off + bytes + 255) & ~(size_t)255;
        return p;
    };
    float* degw = (float*)alloc(N_NODES * 4);
    int*   cnt  = (int*)alloc(N_NODES * 4);
    int*   rp   = (int*)alloc((N_NODES + 1) * 4);
    int*   cur  = (int*)alloc(N_NODES * 4);
    int*   part = (int*)alloc(256 * 4);
    float* dinv = (float*)alloc(N_NODES * 4);
    int*   flag = (int*)alloc(4);
    int*   ei32 = (int*)alloc((size_t)2 * N_EDGES * 4);
    int*   colp = (int*)alloc((size_t)N_EDGES * 4);
    float* nwp  = (float*)alloc((size_t)N_EDGES * 4);
    unsigned short* XH = (unsigned short*)alloc((size_t)N_PAD * 128 * 2);
    unsigned short* U1 = (unsigned short*)alloc((size_t)N_PAD * 128 * 2);
    unsigned short* U2 = (unsigned short*)alloc((size_t)N_PAD * 128 * 2);
    unsigned short* Wf = (unsigned short*)alloc((size_t)12 * 16 * 64 * 8 * 2);
    float* ball = (float*)alloc(256 * 4);
    (void)ws_size; (void)in_sizes; (void)n_in; (void)out_size;

    hipMemsetAsync(degw, 0, N_NODES * 4, stream);
    hipMemsetAsync(cnt, 0, N_NODES * 4, stream);
    hipMemsetAsync(flag, 0, 4, stream);

    int nbN  = (N_NODES + 255) / 256;
    int nbE  = (N_EDGES + 255) / 256;
    int nbE2 = (2 * N_EDGES + 255) / 256;

    k_detect<<<1, 256, 0, stream>>>((const int*)ei, flag);
    k_cvt_deg<<<nbE2, 256, 0, stream>>>(ei, flag, w, ei32, degw, cnt);
    k_scan1<<<nbN, 256, 0, stream>>>(cnt, rp, part, degw, dinv);
    k_scan2<<<1, 256, 0, stream>>>(part, nbN);
    k_scan3<<<nbN, 256, 0, stream>>>(rp, part, cur);
    k_scatter<<<nbE, 256, 0, stream>>>(ei32, w, dinv, cur, colp, nwp);
    k_interleave<<<(N_NODES * 32 + 255) / 256, 256, 0, stream>>>(X, H, XH);
    k_wprep<<<49, 256, 0, stream>>>(Wxi, Whi, Wxf, Whf, Wxc, Whc, Wxo, Who,
                                    bxi, bhi, bxf, bhf, bxc, bhc, bxo, bho,
                                    bgi, bgf, bgc, bgo, Wf, ball);
    k_spmv_bf<<<(N_NODES + 3) / 4, 256, 0, stream>>>(XH, U1, rp, colp, nwp);
    k_spmv_bf<<<(N_NODES + 3) / 4, 256, 0, stream>>>(U1, U2, rp, colp, nwp);
    k_gemm_mfma<<<(N_NODES + 63) / 64, 256, 0, stream>>>(XH, U1, U2, Wf, ball, C, out);
}

// Round 3
// 335.095 us; speedup vs baseline: 1.9421x; 1.2554x over previous
//
#include <hip/hip_runtime.h>

#define N_NODES 50000
#define N_PAD   50048
#define N_EDGES 800000

typedef __attribute__((ext_vector_type(8))) short bf16x8;
typedef __attribute__((ext_vector_type(4))) float f32x4;

__device__ __forceinline__ unsigned short f2bf(float f) {
    unsigned u = __float_as_uint(f);
    u = (u + 0x7fffu + ((u >> 16) & 1u)) >> 16;
    return (unsigned short)u;
}

// ---------------------------------------------------------------- edge utils

__global__ __launch_bounds__(256) void k_detect(const int* __restrict__ ei, int* __restrict__ flag) {
    int t = threadIdx.x;
    int v = 0;
    for (int i = 1 + 2 * t; i < 8192; i += 512) v |= ei[i];
    if (v) atomicOr(flag, 1);
}

// one u64 atomic per edge: hi32 = count (old value = this edge's rank in its row),
// lo32 = fixed-point (2^-22) weighted-degree sum. Replaces degw+cnt+scatter atomics.
__global__ __launch_bounds__(256) void k_deg_rank(const void* __restrict__ eiraw, const int* __restrict__ flag,
                                                  const float* __restrict__ w,
                                                  unsigned long long* __restrict__ packed,
                                                  unsigned* __restrict__ rank) {
    int e = blockIdx.x * 256 + threadIdx.x;
    if (e >= N_EDGES) return;
    int r = (*flag) ? ((const int*)eiraw)[e] : (int)(((const long long*)eiraw)[e]);
    unsigned qw = (unsigned)(w[e] * 4194304.f + 0.5f);
    unsigned long long old = atomicAdd(&packed[r], (1ull << 32) | (unsigned long long)qw);
    rank[e] = (unsigned)(old >> 32);
}

// ---------------------------------------------------------------- CSR build (scan over counts)

__global__ __launch_bounds__(256) void k_scan1(const unsigned long long* __restrict__ packed,
                                               int* __restrict__ rp, int* __restrict__ part,
                                               float* __restrict__ dinv) {
    __shared__ int s[256];
    int t = threadIdx.x, i = blockIdx.x * 256 + t;
    unsigned long long p = (i < N_NODES) ? packed[i] : 0ull;
    int v = (int)(p >> 32);
    s[t] = v; __syncthreads();
    for (int d = 1; d < 256; d <<= 1) {
        int add = (t >= d) ? s[t - d] : 0;
        __syncthreads();
        s[t] += add;
        __syncthreads();
    }
    if (i < N_NODES) {
        rp[i] = s[t] - v;
        float dg = (float)(unsigned)(p & 0xffffffffu) * (1.f / 4194304.f);
        dinv[i] = (dg > 0.f) ? rsqrtf(dg) : 0.f;
    }
    if (t == 255) part[blockIdx.x] = s[255];
}

__global__ __launch_bounds__(256) void k_scan2(int* __restrict__ part, int nb) {
    __shared__ int s[256];
    int t = threadIdx.x;
    int v = (t < nb) ? part[t] : 0;
    s[t] = v; __syncthreads();
    for (int d = 1; d < 256; d <<= 1) {
        int add = (t >= d) ? s[t - d] : 0;
        __syncthreads();
        s[t] += add;
        __syncthreads();
    }
    if (t < nb) part[t] = s[t] - v;
}

__global__ __launch_bounds__(256) void k_scan3(int* __restrict__ rp, const int* __restrict__ part) {
    int i = blockIdx.x * 256 + threadIdx.x;
    if (i < N_NODES) rp[i] += part[blockIdx.x];
    if (i == 0) rp[N_NODES] = N_EDGES;
}

// atomic-free scatter: pos = rp[row] + rank[e]
__global__ __launch_bounds__(256) void k_scatter(const void* __restrict__ eiraw, const int* __restrict__ flag,
                                                 const float* __restrict__ w, const unsigned* __restrict__ rank,
                                                 const float* __restrict__ dinv, const int* __restrict__ rp,
                                                 int* __restrict__ colp, float* __restrict__ nwp) {
    int e = blockIdx.x * 256 + threadIdx.x;
    if (e >= N_EDGES) return;
    int r, c;
    if (*flag) { r = ((const int*)eiraw)[e]; c = ((const int*)eiraw)[N_EDGES + e]; }
    else       { r = (int)(((const long long*)eiraw)[e]); c = (int)(((const long long*)eiraw)[N_EDGES + e]); }
    int pos = rp[r] + (int)rank[e];
    colp[pos] = c;
    nwp[pos] = dinv[r] * w[e] * dinv[c];
}

// ---------------------------------------------------------------- prep: interleave X||H -> bf16 [node][128]
// + weight fold + pre-swizzle to MFMA B-frag order (merged into one dispatch).
// Wf layout: [ks(12)][nt(16)][lane(64)][j(8)] bf16, lane holds B[k=ks*32+(l>>4)*8+j][n=nt*16+(l&15)].
// T0=V, T1=-U1, T2=2*U2-V fold: b=0: W[0]-W[2]  b=1: -W[1]  b=2: 2*W[2]

#define NB_IL 6250   // N_NODES*32/256

__global__ __launch_bounds__(256) void k_prep(
    const float* __restrict__ X, const float* __restrict__ H, unsigned short* __restrict__ XH,
    const float* __restrict__ Wxi, const float* __restrict__ Whi,
    const float* __restrict__ Wxf, const float* __restrict__ Whf,
    const float* __restrict__ Wxc, const float* __restrict__ Whc,
    const float* __restrict__ Wxo, const float* __restrict__ Who,
    const float* __restrict__ bxi, const float* __restrict__ bhi,
    const float* __restrict__ bxf, const float* __restrict__ bhf,
    const float* __restrict__ bxc, const float* __restrict__ bhc,
    const float* __restrict__ bxo, const float* __restrict__ bho,
    const float* __restrict__ bgi, const float* __restrict__ bgf,
    const float* __restrict__ bgc, const float* __restrict__ bgo,
    unsigned short* __restrict__ Wf, float* __restrict__ ball) {
    int b = blockIdx.x, t = threadIdx.x;
    if (b < NB_IL) {
        int tt = b * 256 + t;                    // one thread per 4 channels
        int node = tt >> 5, g = tt & 31;
        float4 v = (g < 16) ? *(const float4*)(X + (size_t)node * 64 + g * 4)
                            : *(const float4*)(H + (size_t)node * 64 + (g - 16) * 4);
        ushort4 o;
        o.x = f2bf(v.x); o.y = f2bf(v.y); o.z = f2bf(v.z); o.w = f2bf(v.w);
        *(ushort4*)(XH + (size_t)node * 128 + g * 4) = o;
        return;
    }
    int bb = b - NB_IL;
    if (bb < 48) {
        int flat = bb * 256 + t;                 // (ks, nt, lane)
        int l = flat & 63, nt = (flat >> 6) & 15, ks = flat >> 10;
        int n = nt * 16 + (l & 15);
        int g = n >> 6, c = n & 63;
        const float* WX = (g == 0) ? Wxi : (g == 1) ? Wxf : (g == 2) ? Wxc : Wxo;
        const float* WH = (g == 0) ? Whi : (g == 1) ? Whf : (g == 2) ? Whc : Who;
        int k0 = ks * 32 + (l >> 4) * 8;
        unsigned short ov[8];
#pragma unroll
        for (int j = 0; j < 8; j++) {
            int k = k0 + j;
            int bsel = k >> 7, ch = k & 127;
            const float* W = (ch < 64) ? WX : WH;
            int kk = ch & 63;
            float v;
            if (bsel == 0)      v = W[kk * 64 + c] - W[2 * 4096 + kk * 64 + c];
            else if (bsel == 1) v = -W[4096 + kk * 64 + c];
            else                v = 2.f * W[2 * 4096 + kk * 64 + c];
            ov[j] = f2bf(v);
        }
        uint4 o;
        o.x = (unsigned)ov[0] | ((unsigned)ov[1] << 16);
        o.y = (unsigned)ov[2] | ((unsigned)ov[3] << 16);
        o.z = (unsigned)ov[4] | ((unsigned)ov[5] << 16);
        o.w = (unsigned)ov[6] | ((unsigned)ov[7] << 16);
        *(uint4*)(Wf + (size_t)flat * 8) = o;
    } else {
        int g = t >> 6, c = t & 63;
        const float* BX = (g == 0) ? bxi : (g == 1) ? bxf : (g == 2) ? bxc : bxo;
        const float* BH = (g == 0) ? bhi : (g == 1) ? bhf : (g == 2) ? bhc : bho;
        const float* BG = (g == 0) ? bgi : (g == 1) ? bgf : (g == 2) ? bgc : bgo;
        ball[t] = BX[c] + BH[c] + BG[c];
    }
}

// ---------------------------------------------------------------- SpMV: dst = A * src (bf16 in/out, fp32 accum)
// one wave per node; lane owns channel pair; 4-edge unroll = 4 independent 256B gathers in flight.

__global__ __launch_bounds__(256) void k_spmv_bf(const unsigned short* __restrict__ src,
                                                 unsigned short* __restrict__ dst,
                                                 const int* __restrict__ rp, const int* __restrict__ colp,
                                                 const float* __restrict__ nwp) {
    int wid = threadIdx.x >> 6, lane = threadIdx.x & 63;
    int node = blockIdx.x * 4 + wid;
    if (node >= N_NODES) return;
    int s = rp[node], e = rp[node + 1];
    float a0 = 0.f, a1 = 0.f;
    int j = s;
    for (; j + 4 <= e; j += 4) {
        int c0 = colp[j], c1 = colp[j + 1], c2 = colp[j + 2], c3 = colp[j + 3];
        float w0 = nwp[j], w1 = nwp[j + 1], w2 = nwp[j + 2], w3 = nwp[j + 3];
        unsigned v0 = *(const unsigned*)(src + (size_t)c0 * 128 + lane * 2);
        unsigned v1 = *(const unsigned*)(src + (size_t)c1 * 128 + lane * 2);
        unsigned v2 = *(const unsigned*)(src + (size_t)c2 * 128 + lane * 2);
        unsigned v3 = *(const unsigned*)(src + (size_t)c3 * 128 + lane * 2);
        a0 = fmaf(w0, __uint_as_float(v0 << 16), a0);
        a1 = fmaf(w0, __uint_as_float(v0 & 0xffff0000u), a1);
        a0 = fmaf(w1, __uint_as_float(v1 << 16), a0);
        a1 = fmaf(w1, __uint_as_float(v1 & 0xffff0000u), a1);
        a0 = fmaf(w2, __uint_as_float(v2 << 16), a0);
        a1 = fmaf(w2, __uint_as_float(v2 & 0xffff0000u), a1);
        a0 = fmaf(w3, __uint_as_float(v3 << 16), a0);
        a1 = fmaf(w3, __uint_as_float(v3 & 0xffff0000u), a1);
    }
    for (; j < e; j++) {
        int c0 = colp[j];
        float w0 = nwp[j];
        unsigned v0 = *(const unsigned*)(src + (size_t)c0 * 128 + lane * 2);
        a0 = fmaf(w0, __uint_as_float(v0 << 16), a0);
        a1 = fmaf(w0, __uint_as_float(v0 & 0xffff0000u), a1);
    }
    unsigned o = (unsigned)f2bf(a0) | ((unsigned)f2bf(a1) << 16);
    *(unsigned*)(dst + (size_t)node * 128 + lane * 2) = o;
}

// ---------------------------------------------------------------- MFMA GEMM [50000,384]@[384,256] + LSTM gates
// block = 4 waves; wave = 16 rows x 256 cols = 16 acc tiles of 16x16.
// A-frag: direct global b128 (lane's 8 k-elems are contiguous). B: LDS-staged pre-swizzled frags.

__global__ __launch_bounds__(256) void k_gemm_mfma(
    const unsigned short* __restrict__ XH, const unsigned short* __restrict__ U1,
    const unsigned short* __restrict__ U2, const unsigned short* __restrict__ Wf,
    const float* __restrict__ ball, const float* __restrict__ C, float* __restrict__ out) {
    __shared__ __align__(16) unsigned short Bs[8192];   // 16 KB, one k-step of B-frags

    int t = threadIdx.x;
    int wid = t >> 6, lane = t & 63;
    int col = lane & 15, quad = lane >> 4;
    int m0 = blockIdx.x * 64 + wid * 16;
    int arow = m0 + col;

    f32x4 acc[16];
#pragma unroll
    for (int i = 0; i < 16; i++) acc[i] = (f32x4){0.f, 0.f, 0.f, 0.f};

    const unsigned short* srcs[3] = {XH, U1, U2};

    bf16x8 a_cur = *(const bf16x8*)(srcs[0] + (size_t)arow * 128 + quad * 8);

    for (int ks = 0; ks < 12; ks++) {
        __syncthreads();
        const uint4* gsrc = (const uint4*)(Wf + (size_t)ks * 8192);
        uint4 st0 = gsrc[t], st1 = gsrc[t + 256], st2 = gsrc[t + 512], st3 = gsrc[t + 768];
        ((uint4*)Bs)[t] = st0; ((uint4*)Bs)[t + 256] = st1;
        ((uint4*)Bs)[t + 512] = st2; ((uint4*)Bs)[t + 768] = st3;
        bf16x8 a_nxt = a_cur;
        if (ks < 11) {
            int ks1 = ks + 1;
            a_nxt = *(const bf16x8*)(srcs[ks1 >> 2] + (size_t)arow * 128 + (ks1 & 3) * 32 + quad * 8);
        }
        __syncthreads();
#pragma unroll
        for (int nt = 0; nt < 16; nt++) {
            bf16x8 bfrag = *(const bf16x8*)(Bs + nt * 512 + lane * 8);
            acc[nt] = __builtin_amdgcn_mfma_f32_16x16x32_bf16(a_cur, bfrag, acc[nt], 0, 0, 0);
        }
        a_cur = a_nxt;
    }

    float bI[4], bF[4], bT[4], bO[4];
#pragma unroll
    for (int cq = 0; cq < 4; cq++) {
        int c = cq * 16 + col;
        bI[cq] = ball[c]; bF[cq] = ball[64 + c]; bT[cq] = ball[128 + c]; bO[cq] = ball[192 + c];
    }
#pragma unroll
    for (int r = 0; r < 4; r++) {
        int node = m0 + quad * 4 + r;
        if (node >= N_NODES) continue;
#pragma unroll
        for (int cq = 0; cq < 4; cq++) {
            int c = cq * 16 + col;
            float Ip = acc[0 + cq][r]  + bI[cq];
            float Fp = acc[4 + cq][r]  + bF[cq];
            float Tp = acc[8 + cq][r]  + bT[cq];
            float Op = acc[12 + cq][r] + bO[cq];
            float ig = 1.f / (1.f + __expf(-Ip));
            float fg = 1.f / (1.f + __expf(-Fp));
            float tg = tanhf(Tp);
            float og = 1.f / (1.f + __expf(-Op));
            float cv = fmaf(fg, C[(size_t)node * 64 + c], ig * tg);
            out[(size_t)node * 64 + c] = og * tanhf(cv);
            out[(size_t)N_NODES * 64 + (size_t)node * 64 + c] = cv;
        }
    }
}

// ---------------------------------------------------------------- launch

extern "C" void kernel_launch(void* const* d_in, const int* in_sizes, int n_in,
                              void* d_out, int out_size, void* d_ws, size_t ws_size,
                              hipStream_t stream) {
    const float* X   = (const float*)d_in[0];
    const void*  ei  = d_in[1];
    const float* w   = (const float*)d_in[2];
    const float* H   = (const float*)d_in[3];
    const float* C   = (const float*)d_in[4];
    const float* Wxi = (const float*)d_in[5];  const float* bxi = (const float*)d_in[6];
    const float* Whi = (const float*)d_in[7];  const float* bhi = (const float*)d_in[8];
    const float* Wxf = (const float*)d_in[9];  const float* bxf = (const float*)d_in[10];
    const float* Whf = (const float*)d_in[11]; const float* bhf = (const float*)d_in[12];
    const float* Wxc = (const float*)d_in[13]; const float* bxc = (const float*)d_in[14];
    const float* Whc = (const float*)d_in[15]; const float* bhc = (const float*)d_in[16];
    const float* Wxo = (const float*)d_in[17]; const float* bxo = (const float*)d_in[18];
    const float* Who = (const float*)d_in[19]; const float* bho = (const float*)d_in[20];
    const float* bgi = (const float*)d_in[21]; const float* bgf = (const float*)d_in[22];
    const float* bgc = (const float*)d_in[23]; const float* bgo = (const float*)d_in[24];
    float* out = (float*)d_out;

    char* ws = (char*)d_ws;
    size_t off = 0;
    auto alloc = [&](size_t bytes) -> char* {
        char* p = ws + off;
        off = (off + bytes + 255) & ~(size_t)255;
        return p;
    };
    unsigned long long* packed = (unsigned long long*)alloc((size_t)N_NODES * 8);
    unsigned* rank = (unsigned*)alloc((size_t)N_EDGES * 4);
    int*   rp   = (int*)alloc((N_NODES + 1) * 4);
    int*   part = (int*)alloc(256 * 4);
    float* dinv = (float*)alloc(N_NODES * 4);
    int*   flag = (int*)alloc(4);
    int*   colp = (int*)alloc((size_t)N_EDGES * 4);
    float* nwp  = (float*)alloc((size_t)N_EDGES * 4);
    unsigned short* XH = (unsigned short*)alloc((size_t)N_PAD * 128 * 2);
    unsigned short* U1 = (unsigned short*)alloc((size_t)N_PAD * 128 * 2);
    unsigned short* U2 = (unsigned short*)alloc((size_t)N_PAD * 128 * 2);
    unsigned short* Wf = (unsigned short*)alloc((size_t)12 * 16 * 64 * 8 * 2);
    float* ball = (float*)alloc(256 * 4);
    (void)ws_size; (void)in_sizes; (void)n_in; (void)out_size;

    hipMemsetAsync(packed, 0, (size_t)N_NODES * 8, stream);
    hipMemsetAsync(flag, 0, 4, stream);

    int nbN = (N_NODES + 255) / 256;
    int nbE = (N_EDGES + 255) / 256;

    k_detect<<<1, 256, 0, stream>>>((const int*)ei, flag);
    k_deg_rank<<<nbE, 256, 0, stream>>>(ei, flag, w, packed, rank);
    k_scan1<<<nbN, 256, 0, stream>>>(packed, rp, part, dinv);
    k_scan2<<<1, 256, 0, stream>>>(part, nbN);
    k_scan3<<<nbN, 256, 0, stream>>>(rp, part);
    k_scatter<<<nbE, 256, 0, stream>>>(ei, flag, w, rank, dinv, rp, colp, nwp);
    k_prep<<<NB_IL + 49, 256, 0, stream>>>(X, H, XH,
                                           Wxi, Whi, Wxf, Whf, Wxc, Whc, Wxo, Who,
                                           bxi, bhi, bxf, bhf, bxc, bhc, bxo, bho,
                                           bgi, bgf, bgc, bgo, Wf, ball);
    k_spmv_bf<<<(N_NODES + 3) / 4, 256, 0, stream>>>(XH, U1, rp, colp, nwp);
    k_spmv_bf<<<(N_NODES + 3) / 4, 256, 0, stream>>>(U1, U2, rp, colp, nwp);
    k_gemm_mfma<<<(N_NODES + 63) / 64, 256, 0, stream>>>(XH, U1, U2, Wf, ball, C, out);
}

// Round 4
// 294.942 us; speedup vs baseline: 2.2065x; 1.1361x over previous
//
#include <hip/hip_runtime.h>

#define N_NODES 50000
#define N_PAD   50048
#define N_EDGES 800000
#define NBE     3125    // edge blocks
#define NB_IL   6250    // interleave blocks (N_NODES*32/256)

typedef __attribute__((ext_vector_type(8))) short bf16x8;
typedef __attribute__((ext_vector_type(4))) float f32x4;

__device__ __forceinline__ unsigned short f2bf(float f) {
    unsigned u = __float_as_uint(f);
    u = (u + 0x7fffu + ((u >> 16) & 1u)) >> 16;
    return (unsigned short)u;
}

__device__ __forceinline__ float fsig(float x) {          // fast sigmoid
    x = fminf(fmaxf(x, -30.f), 30.f);
    float t = __expf(x);
    return __fdividef(t, 1.f + t);
}
__device__ __forceinline__ float ftanh(float x) {         // fast tanh
    x = fminf(fmaxf(x, -15.f), 15.f);
    float t = __expf(2.f * x);
    return 1.f - __fdividef(2.f, t + 1.f);
}

// per-block int32/int64 detect: int64 edge_index => odd 32-bit words all zero
__device__ __forceinline__ int block_is_i32(const int* __restrict__ eiv, int t, int* sflag) {
    if (t == 0) *sflag = 0;
    __syncthreads();
    int v = eiv[1 + 2 * t];            // sample odd words 1..511
    if (v) atomicOr(sflag, 1);
    __syncthreads();
    return *sflag;
}

// ---------------------------------------------------------------- merged: deg_rank || interleave || wprep
// deg_rank: one u64 atomic per edge (hi=count -> rank, lo=fixed-point weighted degree)

__global__ __launch_bounds__(256) void k_deg_prep(
    const void* __restrict__ eiraw, const float* __restrict__ w,
    unsigned long long* __restrict__ packed, unsigned* __restrict__ rank,
    const float* __restrict__ X, const float* __restrict__ H, unsigned short* __restrict__ XH,
    const float* __restrict__ Wxi, const float* __restrict__ Whi,
    const float* __restrict__ Wxf, const float* __restrict__ Whf,
    const float* __restrict__ Wxc, const float* __restrict__ Whc,
    const float* __restrict__ Wxo, const float* __restrict__ Who,
    const float* __restrict__ bxi, const float* __restrict__ bhi,
    const float* __restrict__ bxf, const float* __restrict__ bhf,
    const float* __restrict__ bxc, const float* __restrict__ bhc,
    const float* __restrict__ bxo, const float* __restrict__ bho,
    const float* __restrict__ bgi, const float* __restrict__ bgf,
    const float* __restrict__ bgc, const float* __restrict__ bgo,
    unsigned short* __restrict__ Wf, float* __restrict__ ball) {
    __shared__ int sflag;
    int b = blockIdx.x, t = threadIdx.x;
    if (b < NBE) {
        int is32 = block_is_i32((const int*)eiraw, t, &sflag);
        int e = b * 256 + t;
        if (e >= N_EDGES) return;
        int r = is32 ? ((const int*)eiraw)[e] : (int)(((const long long*)eiraw)[e]);
        unsigned qw = (unsigned)(w[e] * 4194304.f + 0.5f);
        unsigned long long old = atomicAdd(&packed[r], (1ull << 32) | (unsigned long long)qw);
        rank[e] = (unsigned)(old >> 32);
        return;
    }
    int bb = b - NBE;
    if (bb < NB_IL) {
        int tt = bb * 256 + t;                   // one thread per 4 channels
        int node = tt >> 5, g = tt & 31;
        float4 v = (g < 16) ? *(const float4*)(X + (size_t)node * 64 + g * 4)
                            : *(const float4*)(H + (size_t)node * 64 + (g - 16) * 4);
        ushort4 o;
        o.x = f2bf(v.x); o.y = f2bf(v.y); o.z = f2bf(v.z); o.w = f2bf(v.w);
        *(ushort4*)(XH + (size_t)node * 128 + g * 4) = o;
        return;
    }
    bb -= NB_IL;
    if (bb < 48) {
        // Wf layout: [ks(12)][nt(16)][lane(64)][j(8)] bf16; T0=V,T1=-U1,T2=2U2-V fold
        int flat = bb * 256 + t;
        int l = flat & 63, nt = (flat >> 6) & 15, ks = flat >> 10;
        int n = nt * 16 + (l & 15);
        int g = n >> 6, c = n & 63;
        const float* WX = (g == 0) ? Wxi : (g == 1) ? Wxf : (g == 2) ? Wxc : Wxo;
        const float* WH = (g == 0) ? Whi : (g == 1) ? Whf : (g == 2) ? Whc : Who;
        int k0 = ks * 32 + (l >> 4) * 8;
        unsigned short ov[8];
#pragma unroll
        for (int j = 0; j < 8; j++) {
            int k = k0 + j;
            int bsel = k >> 7, ch = k & 127;
            const float* W = (ch < 64) ? WX : WH;
            int kk = ch & 63;
            float v;
            if (bsel == 0)      v = W[kk * 64 + c] - W[2 * 4096 + kk * 64 + c];
            else if (bsel == 1) v = -W[4096 + kk * 64 + c];
            else                v = 2.f * W[2 * 4096 + kk * 64 + c];
            ov[j] = f2bf(v);
        }
        uint4 o;
        o.x = (unsigned)ov[0] | ((unsigned)ov[1] << 16);
        o.y = (unsigned)ov[2] | ((unsigned)ov[3] << 16);
        o.z = (unsigned)ov[4] | ((unsigned)ov[5] << 16);
        o.w = (unsigned)ov[6] | ((unsigned)ov[7] << 16);
        *(uint4*)(Wf + (size_t)flat * 8) = o;
    } else {
        int g = t >> 6, c = t & 63;
        const float* BX = (g == 0) ? bxi : (g == 1) ? bxf : (g == 2) ? bxc : bxo;
        const float* BH = (g == 0) ? bhi : (g == 1) ? bhf : (g == 2) ? bhc : bho;
        const float* BG = (g == 0) ? bgi : (g == 1) ? bgf : (g == 2) ? bgc : bgo;
        ball[t] = BX[c] + BH[c] + BG[c];
    }
}

// ---------------------------------------------------------------- scans (rp stays block-partial; part added downstream)

__global__ __launch_bounds__(256) void k_scan1(const unsigned long long* __restrict__ packed,
                                               int* __restrict__ rp, int* __restrict__ part,
                                               float* __restrict__ dinv) {
    __shared__ int s[256];
    int t = threadIdx.x, i = blockIdx.x * 256 + t;
    unsigned long long p = (i < N_NODES) ? packed[i] : 0ull;
    int v = (int)(p >> 32);
    s[t] = v; __syncthreads();
    for (int d = 1; d < 256; d <<= 1) {
        int add = (t >= d) ? s[t - d] : 0;
        __syncthreads();
        s[t] += add;
        __syncthreads();
    }
    if (i < N_NODES) {
        rp[i] = s[t] - v;                         // exclusive within block
        float dg = (float)(unsigned)(p & 0xffffffffu) * (1.f / 4194304.f);
        dinv[i] = (dg > 0.f) ? rsqrtf(dg) : 0.f;
        if (i == N_NODES - 1) rp[N_NODES] = s[t]; // inclusive partial for last block
    }
    if (t == 255) part[blockIdx.x] = s[255];
}

__global__ __launch_bounds__(256) void k_scan2(int* __restrict__ part, int nb) {
    __shared__ int s[256];
    int t = threadIdx.x;
    int v = (t < nb) ? part[t] : 0;
    s[t] = v; __syncthreads();
    for (int d = 1; d < 256; d <<= 1) {
        int add = (t >= d) ? s[t - d] : 0;
        __syncthreads();
        s[t] += add;
        __syncthreads();
    }
    if (t < nb) part[t] = s[t] - v;
}

// atomic-free scatter: pos = rp[r] + part[r>>8] + rank[e]
__global__ __launch_bounds__(256) void k_scatter(const void* __restrict__ eiraw, const float* __restrict__ w,
                                                 const unsigned* __restrict__ rank,
                                                 const float* __restrict__ dinv, const int* __restrict__ rp,
                                                 const int* __restrict__ part,
                                                 int* __restrict__ colp, float* __restrict__ nwp) {
    __shared__ int sflag;
    int t = threadIdx.x;
    int is32 = block_is_i32((const int*)eiraw, t, &sflag);
    int e = blockIdx.x * 256 + t;
    if (e >= N_EDGES) return;
    int r, c;
    if (is32) { r = ((const int*)eiraw)[e]; c = ((const int*)eiraw)[N_EDGES + e]; }
    else      { r = (int)(((const long long*)eiraw)[e]); c = (int)(((const long long*)eiraw)[N_EDGES + e]); }
    int pos = rp[r] + part[r >> 8] + (int)rank[e];
    colp[pos] = c;
    nwp[pos] = dinv[r] * w[e] * dinv[c];
}

// ---------------------------------------------------------------- SpMV: dst = A*src (bf16, fp32 accum)
// one wave per node; lane = channel pair; masked 8-edge groups keep 8 gathers in flight (no serial tail).

__global__ __launch_bounds__(256) void k_spmv_bf(const unsigned short* __restrict__ src,
                                                 unsigned short* __restrict__ dst,
                                                 const int* __restrict__ rp, const int* __restrict__ part,
                                                 const int* __restrict__ colp, const float* __restrict__ nwp) {
    int wid = threadIdx.x >> 6, lane = threadIdx.x & 63;
    int node = blockIdx.x * 4 + wid;
    if (node >= N_NODES) return;
    int s = rp[node] + part[node >> 8];
    int e = rp[node + 1] + part[(node + 1) >> 8];
    float a0 = 0.f, a1 = 0.f;
    for (int jb = s; jb < e; jb += 8) {
        int   c[8]; float wv[8]; unsigned vv[8];
#pragma unroll
        for (int k = 0; k < 8; k++) {
            int j = jb + k;
            int jc = (j < e) ? j : (e - 1);       // clamp: stay in-bounds, weight zeroed
            c[k]  = colp[jc];
            wv[k] = (j < e) ? nwp[jc] : 0.f;
        }
#pragma unroll
        for (int k = 0; k < 8; k++)
            vv[k] = *(const unsigned*)(src + (size_t)c[k] * 128 + lane * 2);
#pragma unroll
        for (int k = 0; k < 8; k++) {
            a0 = fmaf(wv[k], __uint_as_float(vv[k] << 16), a0);
            a1 = fmaf(wv[k], __uint_as_float(vv[k] & 0xffff0000u), a1);
        }
    }
    unsigned o = (unsigned)f2bf(a0) | ((unsigned)f2bf(a1) << 16);
    *(unsigned*)(dst + (size_t)node * 128 + lane * 2) = o;
}

// ---------------------------------------------------------------- MFMA GEMM [50000,384]@[384,256] + LSTM gates
// block = 4 waves; wave = 16 rows x 256 cols (16 acc tiles). A direct global b128; B double-buffered LDS,
// ONE barrier per k-step (barrier's lgkmcnt drain orders reads of buf[k&1] before stores at k+2).

__global__ __launch_bounds__(256) void k_gemm_mfma(
    const unsigned short* __restrict__ XH, const unsigned short* __restrict__ U1,
    const unsigned short* __restrict__ U2, const unsigned short* __restrict__ Wf,
    const float* __restrict__ ball, const float* __restrict__ C, float* __restrict__ out) {
    __shared__ __align__(16) uint4 Bs[2][1024];   // 2 x 16 KB

    int t = threadIdx.x;
    int wid = t >> 6, lane = t & 63;
    int col = lane & 15, quad = lane >> 4;
    int m0 = blockIdx.x * 64 + wid * 16;
    int arow = m0 + col;

    f32x4 acc[16];
#pragma unroll
    for (int i = 0; i < 16; i++) acc[i] = (f32x4){0.f, 0.f, 0.f, 0.f};

    const unsigned short* srcs[3] = {XH, U1, U2};

    bf16x8 a_cur = *(const bf16x8*)(srcs[0] + (size_t)arow * 128 + quad * 8);
    const uint4* g0 = (const uint4*)Wf;
    uint4 p0 = g0[t], p1 = g0[t + 256], p2 = g0[t + 512], p3 = g0[t + 768];

    for (int ks = 0; ks < 12; ks++) {
        uint4* dstb = Bs[ks & 1];
        dstb[t] = p0; dstb[t + 256] = p1; dstb[t + 512] = p2; dstb[t + 768] = p3;
        __syncthreads();
        bf16x8 a_nxt = a_cur;
        if (ks < 11) {
            int ks1 = ks + 1;
            const uint4* g = (const uint4*)(Wf + (size_t)ks1 * 8192);
            p0 = g[t]; p1 = g[t + 256]; p2 = g[t + 512]; p3 = g[t + 768];
            a_nxt = *(const bf16x8*)(srcs[ks1 >> 2] + (size_t)arow * 128 + (ks1 & 3) * 32 + quad * 8);
        }
        const unsigned short* B = (const unsigned short*)Bs[ks & 1];
#pragma unroll
        for (int nt = 0; nt < 16; nt++) {
            bf16x8 bfrag = *(const bf16x8*)(B + nt * 512 + lane * 8);
            acc[nt] = __builtin_amdgcn_mfma_f32_16x16x32_bf16(a_cur, bfrag, acc[nt], 0, 0, 0);
        }
        a_cur = a_nxt;
    }

    // epilogue: acc[g*4+cq][r] = pre-act of gate g, node m0+quad*4+r, channel cq*16+col
    float bI[4], bF[4], bT[4], bO[4];
#pragma unroll
    for (int cq = 0; cq < 4; cq++) {
        int c = cq * 16 + col;
        bI[cq] = ball[c]; bF[cq] = ball[64 + c]; bT[cq] = ball[128 + c]; bO[cq] = ball[192 + c];
    }
#pragma unroll
    for (int r = 0; r < 4; r++) {
        int node = m0 + quad * 4 + r;
        if (node >= N_NODES) continue;
#pragma unroll
        for (int cq = 0; cq < 4; cq++) {
            int c = cq * 16 + col;
            float ig = fsig(acc[0 + cq][r]  + bI[cq]);
            float fg = fsig(acc[4 + cq][r]  + bF[cq]);
            float tg = ftanh(acc[8 + cq][r] + bT[cq]);
            float og = fsig(acc[12 + cq][r] + bO[cq]);
            float cv = fmaf(fg, C[(size_t)node * 64 + c], ig * tg);
            out[(size_t)node * 64 + c] = og * ftanh(cv);
            out[(size_t)N_NODES * 64 + (size_t)node * 64 + c] = cv;
        }
    }
}

// ---------------------------------------------------------------- launch

extern "C" void kernel_launch(void* const* d_in, const int* in_sizes, int n_in,
                              void* d_out, int out_size, void* d_ws, size_t ws_size,
                              hipStream_t stream) {
    const float* X   = (const float*)d_in[0];
    const void*  ei  = d_in[1];
    const float* w   = (const float*)d_in[2];
    const float* H   = (const float*)d_in[3];
    const float* C   = (const float*)d_in[4];
    const float* Wxi = (const float*)d_in[5];  const float* bxi = (const float*)d_in[6];
    const float* Whi = (const float*)d_in[7];  const float* bhi = (const float*)d_in[8];
    const float* Wxf = (const float*)d_in[9];  const float* bxf = (const float*)d_in[10];
    const float* Whf = (const float*)d_in[11]; const float* bhf = (const float*)d_in[12];
    const float* Wxc = (const float*)d_in[13]; const float* bxc = (const float*)d_in[14];
    const float* Whc = (const float*)d_in[15]; const float* bhc = (const float*)d_in[16];
    const float* Wxo = (const float*)d_in[17]; const float* bxo = (const float*)d_in[18];
    const float* Who = (const float*)d_in[19]; const float* bho = (const float*)d_in[20];
    const float* bgi = (const float*)d_in[21]; const float* bgf = (const float*)d_in[22];
    const float* bgc = (const float*)d_in[23]; const float* bgo = (const float*)d_in[24];
    float* out = (float*)d_out;

    char* ws = (char*)d_ws;
    size_t off = 0;
    auto alloc = [&](size_t bytes) -> char* {
        char* p = ws + off;
        off = (off + bytes + 255) & ~(size_t)255;
        return p;
    };
    unsigned long long* packed = (unsigned long long*)alloc((size_t)N_NODES * 8);
    unsigned* rank = (unsigned*)alloc((size_t)N_EDGES * 4);
    int*   rp   = (int*)alloc((N_NODES + 1) * 4);
    int*   part = (int*)alloc(256 * 4);
    float* dinv = (float*)alloc(N_NODES * 4);
    int*   colp = (int*)alloc((size_t)(N_EDGES + 8) * 4);
    float* nwp  = (float*)alloc((size_t)(N_EDGES + 8) * 4);
    unsigned short* XH = (unsigned short*)alloc((size_t)N_PAD * 128 * 2);
    unsigned short* U1 = (unsigned short*)alloc((size_t)N_PAD * 128 * 2);
    unsigned short* U2 = (unsigned short*)alloc((size_t)N_PAD * 128 * 2);
    unsigned short* Wf = (unsigned short*)alloc((size_t)12 * 16 * 64 * 8 * 2);
    float* ball = (float*)alloc(256 * 4);
    (void)ws_size; (void)in_sizes; (void)n_in; (void)out_size;

    hipMemsetAsync(packed, 0, (size_t)N_NODES * 8, stream);

    int nbN = (N_NODES + 255) / 256;

    k_deg_prep<<<NBE + NB_IL + 49, 256, 0, stream>>>(ei, w, packed, rank, X, H, XH,
                                                     Wxi, Whi, Wxf, Whf, Wxc, Whc, Wxo, Who,
                                                     bxi, bhi, bxf, bhf, bxc, bhc, bxo, bho,
                                                     bgi, bgf, bgc, bgo, Wf, ball);
    k_scan1<<<nbN, 256, 0, stream>>>(packed, rp, part, dinv);
    k_scan2<<<1, 256, 0, stream>>>(part, nbN);
    k_scatter<<<NBE, 256, 0, stream>>>(ei, w, rank, dinv, rp, part, colp, nwp);
    k_spmv_bf<<<(N_NODES + 3) / 4, 256, 0, stream>>>(XH, U1, rp, part, colp, nwp);
    k_spmv_bf<<<(N_NODES + 3) / 4, 256, 0, stream>>>(U1, U2, rp, part, colp, nwp);
    k_gemm_mfma<<<(N_NODES + 63) / 64, 256, 0, stream>>>(XH, U1, U2, Wf, ball, C, out);
}